// Round 5
// baseline (658.814 us; speedup 1.0000x reference)
//
#include <hip/hip_runtime.h>
#include <hip/hip_bf16.h>
#include <hip/hip_fp16.h>

typedef unsigned short u16;
typedef __attribute__((ext_vector_type(8))) short short8;
typedef __attribute__((ext_vector_type(4))) float floatx4;

#define DEVI static __device__ __forceinline__

DEVI float bf2f(u16 b) { return __uint_as_float(((unsigned)b) << 16); }
DEVI u16 f2bf(float f) {
  __hip_bfloat16 h = __float2bfloat16(f);
  u16 u; __builtin_memcpy(&u, &h, 2); return u;
}
DEVI u16 f2h(float f) {
  __half h = __float2half(f);
  u16 u; __builtin_memcpy(&u, &h, 2); return u;
}

// ---------------- weight transpose + fp32->bf16: dst[C][R] = bf16(src[R][C]^T) ----------------
struct TransArgs {
  const float* src[10];
  u16* dst[10];
  int R[10];
  int C[10];
};

__global__ __launch_bounds__(256) void transpose_k(TransArgs t) {
  const int z = blockIdx.z;
  const float* __restrict__ src = t.src[z];
  u16* __restrict__ dst = t.dst[z];
  const int R = t.R[z], C = t.C[z];
  const int c0 = blockIdx.x * 32, r0 = blockIdx.y * 32;
  if (c0 >= C || r0 >= R) return;
  __shared__ float tile[32][33];
  const int tx = threadIdx.x & 31, ty = threadIdx.x >> 5;
  for (int i = ty; i < 32; i += 8)
    tile[i][tx] = src[(size_t)(r0 + i) * C + c0 + tx];
  __syncthreads();
  for (int i = ty; i < 32; i += 8)
    dst[(size_t)(c0 + i) * R + r0 + tx] = f2bf(tile[tx][i]);
}

// ------------- GEMM: C[M][N] = act(A[M][K] @ W + bias), WT[N][K] bf16 given -------------
// c_mode: 0 = bf16 out, 1 = fp32 out, 2 = fp16 out
struct GemmArgs {
  const void* A[3];      // fp32 if a_f32 else bf16
  const u16* WT[3];      // bf16
  const float* bias[3];  // fp32
  void* C[3];
};

__global__ __launch_bounds__(256) void gemm_bias_act(GemmArgs ga, int M, int N, int K,
                                                     int relu, int a_f32, int c_mode) {
  const int z = blockIdx.z;
  const void* __restrict__ A = ga.A[z];
  const u16* __restrict__ WT = ga.WT[z];
  const float* __restrict__ bias = ga.bias[z];
  void* __restrict__ C = ga.C[z];

  __shared__ u16 As[64][72];
  __shared__ u16 Bs[64][72];

  const int tid = threadIdx.x;
  const int lane = tid & 63;
  const int wave = tid >> 6;
  const int wm = wave >> 1, wn = wave & 1;
  const int mb = blockIdx.y, nb = blockIdx.x;

  floatx4 acc0 = {0.f, 0.f, 0.f, 0.f}, acc1 = acc0, acc2 = acc0, acc3 = acc0;

  const int sr = tid >> 3;        // 0..31
  const int sc = (tid & 7) * 8;   // 0..56

  for (int k0 = 0; k0 < K; k0 += 64) {
    __syncthreads();
#pragma unroll
    for (int it = 0; it < 2; ++it) {
      const int rr = sr + it * 32;
      if (a_f32) {
        const float* Af = (const float*)A;
        const float4 f0 = *(const float4*)(Af + (size_t)(mb * 64 + rr) * K + k0 + sc);
        const float4 f1 = *(const float4*)(Af + (size_t)(mb * 64 + rr) * K + k0 + sc + 4);
        u16 tmp[8] = {f2bf(f0.x), f2bf(f0.y), f2bf(f0.z), f2bf(f0.w),
                      f2bf(f1.x), f2bf(f1.y), f2bf(f1.z), f2bf(f1.w)};
        int4 t; __builtin_memcpy(&t, tmp, 16);
        *(int4*)&As[rr][sc] = t;
      } else {
        const u16* Ab = (const u16*)A;
        *(int4*)&As[rr][sc] = *(const int4*)(Ab + (size_t)(mb * 64 + rr) * K + k0 + sc);
      }
      *(int4*)&Bs[rr][sc] = *(const int4*)(WT + (size_t)(nb * 64 + rr) * K + k0 + sc);
    }
    __syncthreads();
#pragma unroll
    for (int ks = 0; ks < 2; ++ks) {
      const int koff = ks * 32 + (lane >> 4) * 8;
      const int am = wm * 32 + (lane & 15);
      const int bn = wn * 32 + (lane & 15);
      short8 a0 = *(const short8*)&As[am][koff];
      short8 a1 = *(const short8*)&As[am + 16][koff];
      short8 b0 = *(const short8*)&Bs[bn][koff];
      short8 b1 = *(const short8*)&Bs[bn + 16][koff];
      acc0 = __builtin_amdgcn_mfma_f32_16x16x32_bf16(a0, b0, acc0, 0, 0, 0);
      acc1 = __builtin_amdgcn_mfma_f32_16x16x32_bf16(a0, b1, acc1, 0, 0, 0);
      acc2 = __builtin_amdgcn_mfma_f32_16x16x32_bf16(a1, b0, acc2, 0, 0, 0);
      acc3 = __builtin_amdgcn_mfma_f32_16x16x32_bf16(a1, b1, acc3, 0, 0, 0);
    }
  }

  const int colb = nb * 64 + wn * 32 + (lane & 15);
  const int rowb = mb * 64 + wm * 32 + (lane >> 4) * 4;
  const floatx4 accs[4] = {acc0, acc1, acc2, acc3};
#pragma unroll
  for (int mg = 0; mg < 2; ++mg) {
#pragma unroll
    for (int ng = 0; ng < 2; ++ng) {
      const int col = colb + ng * 16;
      const float bv = bias[col];
      const floatx4 v = accs[mg * 2 + ng];
#pragma unroll
      for (int r = 0; r < 4; ++r) {
        const int row = rowb + mg * 16 + r;
        float x = v[r] + bv;
        if (relu) x = fmaxf(x, 0.f);
        if (c_mode == 1)      ((float*)C)[(size_t)row * N + col] = x;
        else if (c_mode == 2) ((u16*)C)[(size_t)row * N + col] = f2h(x);
        else                  ((u16*)C)[(size_t)row * N + col] = f2bf(x);
      }
    }
  }
}

// ---------------- fused attention v3 ----------------
// K,Q,V are fp16 [b*1024][512]. Lane = (qg in 0..7, s in 0..7): queries {j0+qg, j0+qg+8},
// feature slice s (feats [s*64, s*64+64)). Q in regs; K,V read direct from global (L2).
// Per 4-key batch: phase1 per-lane fp16 L1 partials -> LDS pd exchange -> owner lane
// (q=lane&15, k2=lane>>4) reduces + softmaxes -> w to LDS -> phase2 packed fp16 PV.
// Wave-private LDS regions, zero main-loop barriers, zero shuffles.
__global__ __launch_bounds__(256, 2) void attn_kernel(const u16* __restrict__ Km,
                                                      const u16* __restrict__ Qm,
                                                      const u16* __restrict__ Vm,
                                                      float* __restrict__ partial) {
  __shared__ alignas(16) u16 lds[24576];   // 48 KB: 4 waves x (pd 4096 + wb 512) halfs; reused for o-reduce

  const int tid = threadIdx.x;
  const int lane = tid & 63;
  const int wave = tid >> 6;
  const int bid = blockIdx.x;      // qt(6) | sp(1) | b(2)
  const int qt = bid & 63;
  const int sp = (bid >> 6) & 1;
  const int b = bid >> 7;
  const int j0 = qt * 16;
  const int qg = lane >> 3;
  const int s = lane & 7;

  // Q into registers: 2 queries x 8 granules of this lane's 64-feat slice
  int4 Qreg[2][8];
#pragma unroll
  for (int qi = 0; qi < 2; ++qi) {
    const u16* qrow = Qm + (size_t)(b * 1024 + j0 + qg + qi * 8) * 512 + s * 64;
#pragma unroll
    for (int pi = 0; pi < 8; ++pi)
      Qreg[qi][pi] = *(const int4*)(qrow + pi * 8);
  }

  __half2 o[2][8][4];
#pragma unroll
  for (int qi = 0; qi < 2; ++qi)
#pragma unroll
    for (int pi = 0; pi < 8; ++pi)
#pragma unroll
      for (int j = 0; j < 4; ++j) o[qi][pi][j] = __float2half2_rn(0.f);

  u16* pd = lds + wave * 4608;     // [k2][q][s][8h] halfs: ((k2*16+q)*8+s)*8
  u16* wb = pd + 4096;             // [k2][q][8h] halfs: (k2*16+q)*8

  const int keyBase = b * 1024 + sp * 512 + wave * 128;
  const int qo = lane & 15;        // owner cell: query
  const int k2o = lane >> 4;       // owner cell: key within batch

#pragma unroll 1
  for (int batch = 0; batch < 32; ++batch) {
    const int k0 = keyBase + batch * 4;

    // ---- phase 1: per-lane L1 partials over 64-feat slice, 4 keys
#pragma unroll
    for (int k2 = 0; k2 < 4; ++k2) {
      const u16* krow = Km + (size_t)(k0 + k2) * 512 + s * 64;
      __half2 acc[2][4];
#pragma unroll
      for (int qi = 0; qi < 2; ++qi)
#pragma unroll
        for (int j = 0; j < 4; ++j) acc[qi][j] = __float2half2_rn(0.f);
#pragma unroll
      for (int pi = 0; pi < 8; ++pi) {
        const int4 kv = *(const int4*)(krow + pi * 8);
        const __half2* kh = reinterpret_cast<const __half2*>(&kv);
#pragma unroll
        for (int qi = 0; qi < 2; ++qi) {
          const __half2* qh = reinterpret_cast<const __half2*>(&Qreg[qi][pi]);
          acc[qi][0] = __hadd2(acc[qi][0], __habs2(__hsub2(kh[0], qh[0])));
          acc[qi][1] = __hadd2(acc[qi][1], __habs2(__hsub2(kh[1], qh[1])));
          acc[qi][2] = __hadd2(acc[qi][2], __habs2(__hsub2(kh[2], qh[2])));
          acc[qi][3] = __hadd2(acc[qi][3], __habs2(__hsub2(kh[3], qh[3])));
        }
      }
#pragma unroll
      for (int qi = 0; qi < 2; ++qi) {
        int4 t; __builtin_memcpy(&t, &acc[qi][0], 16);
        *(int4*)(pd + ((k2 * 16 + qg + qi * 8) * 8 + s) * 8) = t;
      }
    }

    // ---- reduce + softmax: owner lane handles cell (qo, k2o)
    {
      const u16* src = pd + ((k2o * 16 + qo) * 8) * 8;
      __half2 r[4];
      {
        const int4 t = *(const int4*)(src);
        __builtin_memcpy(&r[0], &t, 16);
      }
#pragma unroll
      for (int si = 1; si < 8; ++si) {
        const int4 t = *(const int4*)(src + si * 8);
        const __half2* th = reinterpret_cast<const __half2*>(&t);
#pragma unroll
        for (int j = 0; j < 4; ++j) r[j] = __hadd2(r[j], th[j]);
      }
      float p[8];
#pragma unroll
      for (int j = 0; j < 4; ++j) {
        const float2 f = __half22float2(r[j]);
        p[j * 2] = f.x * f.x;
        p[j * 2 + 1] = f.y * f.y;
      }
      float mn = p[0];
#pragma unroll
      for (int h = 1; h < 8; ++h) mn = fminf(mn, p[h]);
      float wg[8], norm = 0.f;
#pragma unroll
      for (int h = 0; h < 8; ++h) { wg[h] = __expf(0.5f * (mn - p[h])); norm += wg[h]; }
      const float inv = 1.0f / norm;   // norm >= 1 (min head contributes 1)
      int4 wpack;
      __half2* wh = reinterpret_cast<__half2*>(&wpack);
      wh[0] = __floats2half2_rn(wg[0] * inv, wg[1] * inv);
      wh[1] = __floats2half2_rn(wg[2] * inv, wg[3] * inv);
      wh[2] = __floats2half2_rn(wg[4] * inv, wg[5] * inv);
      wh[3] = __floats2half2_rn(wg[6] * inv, wg[7] * inv);
      *(int4*)(wb + (k2o * 16 + qo) * 8) = wpack;
    }

    // ---- phase 2: o += w (x) V over this lane's slice, 4 keys
#pragma unroll
    for (int k2 = 0; k2 < 4; ++k2) {
      const u16* vrow = Vm + (size_t)(k0 + k2) * 512 + s * 64;
      const int4 w0 = *(const int4*)(wb + (k2 * 16 + qg) * 8);
      const int4 w1 = *(const int4*)(wb + (k2 * 16 + qg + 8) * 8);
      const __half2* w0h = reinterpret_cast<const __half2*>(&w0);
      const __half2* w1h = reinterpret_cast<const __half2*>(&w1);
#pragma unroll
      for (int pi = 0; pi < 8; ++pi) {
        const int4 vv = *(const int4*)(vrow + pi * 8);
        const __half2* vh = reinterpret_cast<const __half2*>(&vv);
        o[0][pi][0] = __hfma2(w0h[0], vh[0], o[0][pi][0]);
        o[0][pi][1] = __hfma2(w0h[1], vh[1], o[0][pi][1]);
        o[0][pi][2] = __hfma2(w0h[2], vh[2], o[0][pi][2]);
        o[0][pi][3] = __hfma2(w0h[3], vh[3], o[0][pi][3]);
        o[1][pi][0] = __hfma2(w1h[0], vh[0], o[1][pi][0]);
        o[1][pi][1] = __hfma2(w1h[1], vh[1], o[1][pi][1]);
        o[1][pi][2] = __hfma2(w1h[2], vh[2], o[1][pi][2]);
        o[1][pi][3] = __hfma2(w1h[3], vh[3], o[1][pi][3]);
      }
    }
  }

  // ---- cross-wave tree reduction of o via LDS (regions of 8192 halfs)
  u16* red = lds;
  auto store_o = [&](u16* rg) {
#pragma unroll
    for (int qi = 0; qi < 2; ++qi)
#pragma unroll
      for (int pi = 0; pi < 8; ++pi) {
        int4 t; __builtin_memcpy(&t, &o[qi][pi][0], 16);
        *(int4*)(rg + ((qi * 8 + pi) * 64 + lane) * 8) = t;
      }
  };
  auto add_o = [&](const u16* rg) {
#pragma unroll
    for (int qi = 0; qi < 2; ++qi)
#pragma unroll
      for (int pi = 0; pi < 8; ++pi) {
        const int4 t = *(const int4*)(rg + ((qi * 8 + pi) * 64 + lane) * 8);
        const __half2* th = reinterpret_cast<const __half2*>(&t);
#pragma unroll
        for (int j = 0; j < 4; ++j) o[qi][pi][j] = __hadd2(o[qi][pi][j], th[j]);
      }
  };

  __syncthreads();
  if (wave >= 2) store_o(red + (wave - 2) * 8192);
  __syncthreads();
  if (wave < 2) add_o(red + wave * 8192);
  __syncthreads();
  if (wave == 1) store_o(red + 2 * 8192);
  __syncthreads();
  if (wave == 0) {
    add_o(red + 2 * 8192);
#pragma unroll
    for (int qi = 0; qi < 2; ++qi) {
      const int j = j0 + qg + qi * 8;
      float* dst = partial + ((size_t)sp * 4096 + b * 1024 + j) * 512 + s * 64;
#pragma unroll
      for (int pi = 0; pi < 8; ++pi) {
        const float2 f0 = __half22float2(o[qi][pi][0]);
        const float2 f1 = __half22float2(o[qi][pi][1]);
        const float2 f2 = __half22float2(o[qi][pi][2]);
        const float2 f3 = __half22float2(o[qi][pi][3]);
        *(float4*)(dst + pi * 8) = make_float4(f0.x, f0.y, f1.x, f1.y);
        *(float4*)(dst + pi * 8 + 4) = make_float4(f2.x, f2.y, f3.x, f3.y);
      }
    }
  }
}

// ---------------- reduce: out_pre = bf16(p0 + p1) ----------------
__global__ __launch_bounds__(256) void reduce_k(const float* __restrict__ p,
                                                u16* __restrict__ out) {
  const size_t i = (size_t)blockIdx.x * 256 + threadIdx.x;   // granule of 8
  const float4 a0 = *(const float4*)(p + i * 8);
  const float4 a1 = *(const float4*)(p + i * 8 + 4);
  const float4 b0 = *(const float4*)(p + 2097152 + i * 8);
  const float4 b1 = *(const float4*)(p + 2097152 + i * 8 + 4);
  int4 pk;
  u16* pu = reinterpret_cast<u16*>(&pk);
  pu[0] = f2bf(a0.x + b0.x); pu[1] = f2bf(a0.y + b0.y);
  pu[2] = f2bf(a0.z + b0.z); pu[3] = f2bf(a0.w + b0.w);
  pu[4] = f2bf(a1.x + b1.x); pu[5] = f2bf(a1.y + b1.y);
  pu[6] = f2bf(a1.z + b1.z); pu[7] = f2bf(a1.w + b1.w);
  *(int4*)(out + i * 8) = pk;
}

// ---------------- host ----------------
extern "C" void kernel_launch(void* const* d_in, const int* in_sizes, int n_in,
                              void* d_out, int out_size, void* d_ws, size_t ws_size,
                              hipStream_t stream) {
  (void)in_sizes; (void)n_in; (void)out_size; (void)ws_size;
  char* wsp = (char*)d_ws;
  size_t off = 0;
  auto take = [&](size_t bytes) {
    void* p = (void*)(wsp + off);
    off += ((bytes + 255) & ~(size_t)255);
    return p;
  };

  static const int wR[10] = {128, 512, 512, 128, 512, 512, 128, 512, 512, 512};
  static const int wC[10] = {512, 512, 512, 512, 512, 512, 512, 512, 512, 128};
  static const int widx[10] = {3, 5, 7, 9, 11, 13, 15, 17, 19, 21};

  u16* WT[10];
  for (int i = 0; i < 10; ++i) WT[i] = (u16*)take((size_t)wR[i] * wC[i] * 2);
  u16* h1[3]; for (int i = 0; i < 3; ++i) h1[i] = (u16*)take((size_t)4096 * 512 * 2);
  u16* h2[3]; for (int i = 0; i < 3; ++i) h2[i] = (u16*)take((size_t)4096 * 512 * 2);
  float* partial = (float*)take((size_t)2 * 4096 * 512 * 4);

  TransArgs ta;
  for (int i = 0; i < 10; ++i) {
    ta.src[i] = (const float*)d_in[widx[i]];
    ta.dst[i] = WT[i];
    ta.R[i] = wR[i];
    ta.C[i] = wC[i];
  }
  hipLaunchKernelGGL(transpose_k, dim3(16, 16, 10), dim3(256), 0, stream, ta);

  // layer 1: [4096x128]@[128x512]+b, relu; A fp32  (z: 0=k/KEY, 1=q/QUERY, 2=v/VALUE)
  GemmArgs g1 = {};
  g1.A[0] = d_in[0]; g1.A[1] = d_in[2]; g1.A[2] = d_in[1];
  g1.WT[0] = WT[0]; g1.WT[1] = WT[3]; g1.WT[2] = WT[6];
  g1.bias[0] = (const float*)d_in[4]; g1.bias[1] = (const float*)d_in[10]; g1.bias[2] = (const float*)d_in[16];
  g1.C[0] = h1[0]; g1.C[1] = h1[1]; g1.C[2] = h1[2];
  hipLaunchKernelGGL(gemm_bias_act, dim3(8, 64, 3), dim3(256), 0, stream, g1, 4096, 512, 128, 1, 1, 0);

  // layer 2: [4096x512]@[512x512]+b, relu; A bf16, out bf16
  GemmArgs g2 = {};
  for (int i = 0; i < 3; ++i) { g2.A[i] = h1[i]; g2.C[i] = h2[i]; }
  g2.WT[0] = WT[1]; g2.WT[1] = WT[4]; g2.WT[2] = WT[7];
  g2.bias[0] = (const float*)d_in[6]; g2.bias[1] = (const float*)d_in[12]; g2.bias[2] = (const float*)d_in[18];
  hipLaunchKernelGGL(gemm_bias_act, dim3(8, 64, 3), dim3(256), 0, stream, g2, 4096, 512, 512, 1, 0, 0);

  // layer 3: [4096x512]@[512x512]+b, no act -> Km,Qm,Vm in h1[] as FP16
  GemmArgs g3 = {};
  for (int i = 0; i < 3; ++i) { g3.A[i] = h2[i]; g3.C[i] = h1[i]; }
  g3.WT[0] = WT[2]; g3.WT[1] = WT[5]; g3.WT[2] = WT[8];
  g3.bias[0] = (const float*)d_in[8]; g3.bias[1] = (const float*)d_in[14]; g3.bias[2] = (const float*)d_in[20];
  hipLaunchKernelGGL(gemm_bias_act, dim3(8, 64, 3), dim3(256), 0, stream, g3, 4096, 512, 512, 0, 0, 2);

  // fused attention (2-way key split) -> fp32 partials
  hipLaunchKernelGGL(attn_kernel, dim3(512), dim3(256), 0, stream, h1[0], h1[1], h1[2], partial);

  // reduce partials -> out_pre (bf16) in h2[0]
  hipLaunchKernelGGL(reduce_k, dim3(1024), dim3(256), 0, stream, partial, h2[0]);

  // final projection: [4096x512]@[512x128]+b -> d_out (fp32)
  GemmArgs g4 = {};
  g4.A[0] = h2[0]; g4.WT[0] = WT[9]; g4.bias[0] = (const float*)d_in[22]; g4.C[0] = d_out;
  hipLaunchKernelGGL(gemm_bias_act, dim3(2, 64, 1), dim3(256), 0, stream, g4, 4096, 128, 512, 0, 0, 1);
}

// Round 6
// 512.982 us; speedup vs baseline: 1.2843x; 1.2843x over previous
//
#include <hip/hip_runtime.h>
#include <hip/hip_bf16.h>
#include <hip/hip_fp16.h>

typedef unsigned short u16;
typedef __attribute__((ext_vector_type(8))) short short8;
typedef __attribute__((ext_vector_type(4))) float floatx4;

#define DEVI static __device__ __forceinline__

DEVI float bf2f(u16 b) { return __uint_as_float(((unsigned)b) << 16); }
DEVI u16 f2bf(float f) {
  __hip_bfloat16 h = __float2bfloat16(f);
  u16 u; __builtin_memcpy(&u, &h, 2); return u;
}
DEVI u16 f2h(float f) {
  __half h = __float2half(f);
  u16 u; __builtin_memcpy(&u, &h, 2); return u;
}

// DPP cross-lane add on half2 (VALU pipe, not LDS!)
template <int CTRL>
DEVI __half2 dpp_add_h2(__half2 v) {
  int i; __builtin_memcpy(&i, &v, 4);
  int p = __builtin_amdgcn_update_dpp(0, i, CTRL, 0xF, 0xF, false);
  __half2 pv; __builtin_memcpy(&pv, &p, 4);
  return __hadd2(v, pv);
}

// ---------------- weight transpose + fp32->bf16: dst[C][R] = bf16(src[R][C]^T) ----------------
struct TransArgs {
  const float* src[10];
  u16* dst[10];
  int R[10];
  int C[10];
};

__global__ __launch_bounds__(256) void transpose_k(TransArgs t) {
  const int z = blockIdx.z;
  const float* __restrict__ src = t.src[z];
  u16* __restrict__ dst = t.dst[z];
  const int R = t.R[z], C = t.C[z];
  const int c0 = blockIdx.x * 32, r0 = blockIdx.y * 32;
  if (c0 >= C || r0 >= R) return;
  __shared__ float tile[32][33];
  const int tx = threadIdx.x & 31, ty = threadIdx.x >> 5;
  for (int i = ty; i < 32; i += 8)
    tile[i][tx] = src[(size_t)(r0 + i) * C + c0 + tx];
  __syncthreads();
  for (int i = ty; i < 32; i += 8)
    dst[(size_t)(c0 + i) * R + r0 + tx] = f2bf(tile[tx][i]);
}

// ------------- GEMM: C[M][N] = act(A[M][K] @ W + bias), WT[N][K] bf16 given -------------
// c_mode: 0 = bf16 out, 1 = fp32 out, 2 = fp16 out
struct GemmArgs {
  const void* A[3];      // fp32 if a_f32 else bf16
  const u16* WT[3];      // bf16
  const float* bias[3];  // fp32
  void* C[3];
};

__global__ __launch_bounds__(256) void gemm_bias_act(GemmArgs ga, int M, int N, int K,
                                                     int relu, int a_f32, int c_mode) {
  const int z = blockIdx.z;
  const void* __restrict__ A = ga.A[z];
  const u16* __restrict__ WT = ga.WT[z];
  const float* __restrict__ bias = ga.bias[z];
  void* __restrict__ C = ga.C[z];

  __shared__ u16 As[64][72];
  __shared__ u16 Bs[64][72];

  const int tid = threadIdx.x;
  const int lane = tid & 63;
  const int wave = tid >> 6;
  const int wm = wave >> 1, wn = wave & 1;
  const int mb = blockIdx.y, nb = blockIdx.x;

  floatx4 acc0 = {0.f, 0.f, 0.f, 0.f}, acc1 = acc0, acc2 = acc0, acc3 = acc0;

  const int sr = tid >> 3;        // 0..31
  const int sc = (tid & 7) * 8;   // 0..56

  for (int k0 = 0; k0 < K; k0 += 64) {
    __syncthreads();
#pragma unroll
    for (int it = 0; it < 2; ++it) {
      const int rr = sr + it * 32;
      if (a_f32) {
        const float* Af = (const float*)A;
        const float4 f0 = *(const float4*)(Af + (size_t)(mb * 64 + rr) * K + k0 + sc);
        const float4 f1 = *(const float4*)(Af + (size_t)(mb * 64 + rr) * K + k0 + sc + 4);
        u16 tmp[8] = {f2bf(f0.x), f2bf(f0.y), f2bf(f0.z), f2bf(f0.w),
                      f2bf(f1.x), f2bf(f1.y), f2bf(f1.z), f2bf(f1.w)};
        int4 t; __builtin_memcpy(&t, tmp, 16);
        *(int4*)&As[rr][sc] = t;
      } else {
        const u16* Ab = (const u16*)A;
        *(int4*)&As[rr][sc] = *(const int4*)(Ab + (size_t)(mb * 64 + rr) * K + k0 + sc);
      }
      *(int4*)&Bs[rr][sc] = *(const int4*)(WT + (size_t)(nb * 64 + rr) * K + k0 + sc);
    }
    __syncthreads();
#pragma unroll
    for (int ks = 0; ks < 2; ++ks) {
      const int koff = ks * 32 + (lane >> 4) * 8;
      const int am = wm * 32 + (lane & 15);
      const int bn = wn * 32 + (lane & 15);
      short8 a0 = *(const short8*)&As[am][koff];
      short8 a1 = *(const short8*)&As[am + 16][koff];
      short8 b0 = *(const short8*)&Bs[bn][koff];
      short8 b1 = *(const short8*)&Bs[bn + 16][koff];
      acc0 = __builtin_amdgcn_mfma_f32_16x16x32_bf16(a0, b0, acc0, 0, 0, 0);
      acc1 = __builtin_amdgcn_mfma_f32_16x16x32_bf16(a0, b1, acc1, 0, 0, 0);
      acc2 = __builtin_amdgcn_mfma_f32_16x16x32_bf16(a1, b0, acc2, 0, 0, 0);
      acc3 = __builtin_amdgcn_mfma_f32_16x16x32_bf16(a1, b1, acc3, 0, 0, 0);
    }
  }

  const int colb = nb * 64 + wn * 32 + (lane & 15);
  const int rowb = mb * 64 + wm * 32 + (lane >> 4) * 4;
  const floatx4 accs[4] = {acc0, acc1, acc2, acc3};
#pragma unroll
  for (int mg = 0; mg < 2; ++mg) {
#pragma unroll
    for (int ng = 0; ng < 2; ++ng) {
      const int col = colb + ng * 16;
      const float bv = bias[col];
      const floatx4 v = accs[mg * 2 + ng];
#pragma unroll
      for (int r = 0; r < 4; ++r) {
        const int row = rowb + mg * 16 + r;
        float x = v[r] + bv;
        if (relu) x = fmaxf(x, 0.f);
        if (c_mode == 1)      ((float*)C)[(size_t)row * N + col] = x;
        else if (c_mode == 2) ((u16*)C)[(size_t)row * N + col] = f2h(x);
        else                  ((u16*)C)[(size_t)row * N + col] = f2bf(x);
      }
    }
  }
}

// ---------------- fused attention v4 ----------------
// K,Q,V fp16 [b*1024][512]. Lane = (qg 0..7, s 0..7): queries {j0+qg, j0+qg+8},
// feature slice s (feats [s*64, s*64+64)). Q in regs. Wave-private LDS staging of
// 4-key chunks (K+V, XOR-swizzled granules), register prefetch of next chunk.
// d8 reduced across the 8 s-lanes via DPP (VALU pipe); softmax redundant per lane
// (w stays in registers). Zero main-loop barriers / shuffles / LDS exchanges.
__global__ __launch_bounds__(256, 2) void attn_kernel(const u16* __restrict__ Km,
                                                      const u16* __restrict__ Qm,
                                                      const u16* __restrict__ Vm,
                                                      float* __restrict__ partial) {
  __shared__ alignas(16) u16 lds[24576];   // 48 KB; [wave*4096]: K rows 0..3, V rows at +2048. Reused for o-reduce.

  const int tid = threadIdx.x;
  const int lane = tid & 63;
  const int wave = tid >> 6;
  const int bid = blockIdx.x;      // qt(6) | sp(1) | b(2)
  const int qt = bid & 63;
  const int sp = (bid >> 6) & 1;
  const int b = bid >> 7;
  const int j0 = qt * 16;
  const int qg = lane >> 3;
  const int s = lane & 7;

  // Q into registers: 2 queries x 8 granules of this lane's 64-feat slice
  int4 Qreg[2][8];
#pragma unroll
  for (int qi = 0; qi < 2; ++qi) {
    const u16* qrow = Qm + (size_t)(b * 1024 + j0 + qg + qi * 8) * 512 + s * 64;
#pragma unroll
    for (int pi = 0; pi < 8; ++pi)
      Qreg[qi][pi] = *(const int4*)(qrow + pi * 8);
  }

  __half2 o[2][8][4];
#pragma unroll
  for (int qi = 0; qi < 2; ++qi)
#pragma unroll
    for (int pi = 0; pi < 8; ++pi)
#pragma unroll
      for (int j = 0; j < 4; ++j) o[qi][pi][j] = __float2half2_rn(0.f);

  u16* Kw = lds + wave * 4096;
  u16* Vw = Kw + 2048;
  const int phys = (lane & 56) | ((lane ^ (lane >> 3)) & 7);   // staging swizzle
  const int keyBase = b * 1024 + sp * 512 + wave * 128;

  int4 Kpre[4], Vpre[4];
#pragma unroll
  for (int r = 0; r < 4; ++r) {
    const size_t ga = (size_t)(keyBase + r) * 512 + lane * 8;
    Kpre[r] = *(const int4*)(Km + ga);
    Vpre[r] = *(const int4*)(Vm + ga);
  }

#pragma unroll 1
  for (int c = 0; c < 32; ++c) {
    // stage current chunk (in-order DS ops make single-buffer safe)
#pragma unroll
    for (int r = 0; r < 4; ++r) {
      *(int4*)(Kw + r * 512 + phys * 8) = Kpre[r];
      *(int4*)(Vw + r * 512 + phys * 8) = Vpre[r];
    }
    // prefetch next chunk into regs (hidden under this chunk's ~3000 cyc compute)
    if (c < 31) {
#pragma unroll
      for (int r = 0; r < 4; ++r) {
        const size_t ga = (size_t)(keyBase + (c + 1) * 4 + r) * 512 + lane * 8;
        Kpre[r] = *(const int4*)(Km + ga);
        Vpre[r] = *(const int4*)(Vm + ga);
      }
    }

#pragma unroll
    for (int kk = 0; kk < 4; ++kk) {
      const u16* krow = Kw + kk * 512;
      // ---- phase 1: packed fp16 L1 partials over 64-feat slice
      __half2 acc[2][4];
#pragma unroll
      for (int qi = 0; qi < 2; ++qi)
#pragma unroll
        for (int j = 0; j < 4; ++j) acc[qi][j] = __float2half2_rn(0.f);
#pragma unroll
      for (int pi = 0; pi < 8; ++pi) {
        const int4 kv = *(const int4*)(krow + (s * 8 + (pi ^ s)) * 8);  // logical granule s*8+pi
        const __half2* kh = reinterpret_cast<const __half2*>(&kv);
#pragma unroll
        for (int qi = 0; qi < 2; ++qi) {
          const __half2* qh = reinterpret_cast<const __half2*>(&Qreg[qi][pi]);
          acc[qi][0] = __hadd2(acc[qi][0], __habs2(__hsub2(kh[0], qh[0])));
          acc[qi][1] = __hadd2(acc[qi][1], __habs2(__hsub2(kh[1], qh[1])));
          acc[qi][2] = __hadd2(acc[qi][2], __habs2(__hsub2(kh[2], qh[2])));
          acc[qi][3] = __hadd2(acc[qi][3], __habs2(__hsub2(kh[3], qh[3])));
        }
      }

      // ---- DPP butterfly over the 8 s-lanes (VALU pipe): xor1, xor2, mirror8
#pragma unroll
      for (int qi = 0; qi < 2; ++qi)
#pragma unroll
        for (int j = 0; j < 4; ++j) {
          acc[qi][j] = dpp_add_h2<0xB1>(acc[qi][j]);   // quad_perm [1,0,3,2]
          acc[qi][j] = dpp_add_h2<0x4E>(acc[qi][j]);   // quad_perm [2,3,0,1]
          acc[qi][j] = dpp_add_h2<0x141>(acc[qi][j]);  // row_half_mirror
        }

      // ---- softmax over heads (redundant per lane; w stays in regs)
      __half2 w[2][4];
#pragma unroll
      for (int qi = 0; qi < 2; ++qi) {
        float p[8];
#pragma unroll
        for (int j = 0; j < 4; ++j) {
          const float2 f = __half22float2(acc[qi][j]);
          p[j * 2] = f.x * f.x;
          p[j * 2 + 1] = f.y * f.y;
        }
        float mn = p[0];
#pragma unroll
        for (int h = 1; h < 8; ++h) mn = fminf(mn, p[h]);
        float wg[8], norm = 0.f;
#pragma unroll
        for (int h = 0; h < 8; ++h) { wg[h] = __expf(0.5f * (mn - p[h])); norm += wg[h]; }
        const float inv = __builtin_amdgcn_rcpf(norm);   // norm >= 1
        w[qi][0] = __floats2half2_rn(wg[0] * inv, wg[1] * inv);
        w[qi][1] = __floats2half2_rn(wg[2] * inv, wg[3] * inv);
        w[qi][2] = __floats2half2_rn(wg[4] * inv, wg[5] * inv);
        w[qi][3] = __floats2half2_rn(wg[6] * inv, wg[7] * inv);
      }

      // ---- phase 2: o += w (x) V over this lane's slice
      const u16* vrow = Vw + kk * 512;
#pragma unroll
      for (int pi = 0; pi < 8; ++pi) {
        const int4 vv = *(const int4*)(vrow + (s * 8 + (pi ^ s)) * 8);
        const __half2* vh = reinterpret_cast<const __half2*>(&vv);
        o[0][pi][0] = __hfma2(w[0][0], vh[0], o[0][pi][0]);
        o[0][pi][1] = __hfma2(w[0][1], vh[1], o[0][pi][1]);
        o[0][pi][2] = __hfma2(w[0][2], vh[2], o[0][pi][2]);
        o[0][pi][3] = __hfma2(w[0][3], vh[3], o[0][pi][3]);
        o[1][pi][0] = __hfma2(w[1][0], vh[0], o[1][pi][0]);
        o[1][pi][1] = __hfma2(w[1][1], vh[1], o[1][pi][1]);
        o[1][pi][2] = __hfma2(w[1][2], vh[2], o[1][pi][2]);
        o[1][pi][3] = __hfma2(w[1][3], vh[3], o[1][pi][3]);
      }
    }
  }

  // ---- cross-wave tree reduction of o via LDS (3 regions of 8192 halfs)
  u16* red = lds;
  auto store_o = [&](u16* rg) {
#pragma unroll
    for (int qi = 0; qi < 2; ++qi)
#pragma unroll
      for (int pi = 0; pi < 8; ++pi) {
        int4 t; __builtin_memcpy(&t, &o[qi][pi][0], 16);
        *(int4*)(rg + ((qi * 8 + pi) * 64 + lane) * 8) = t;
      }
  };
  auto add_o = [&](const u16* rg) {
#pragma unroll
    for (int qi = 0; qi < 2; ++qi)
#pragma unroll
      for (int pi = 0; pi < 8; ++pi) {
        const int4 t = *(const int4*)(rg + ((qi * 8 + pi) * 64 + lane) * 8);
        const __half2* th = reinterpret_cast<const __half2*>(&t);
#pragma unroll
        for (int j = 0; j < 4; ++j) o[qi][pi][j] = __hadd2(o[qi][pi][j], th[j]);
      }
  };

  __syncthreads();
  if (wave >= 2) store_o(red + (wave - 2) * 8192);
  __syncthreads();
  if (wave < 2) add_o(red + wave * 8192);
  __syncthreads();
  if (wave == 1) store_o(red + 2 * 8192);
  __syncthreads();
  if (wave == 0) {
    add_o(red + 2 * 8192);
#pragma unroll
    for (int qi = 0; qi < 2; ++qi) {
      const int j = j0 + qg + qi * 8;
      float* dst = partial + ((size_t)sp * 4096 + b * 1024 + j) * 512 + s * 64;
#pragma unroll
      for (int pi = 0; pi < 8; ++pi) {
        const float2 f0 = __half22float2(o[qi][pi][0]);
        const float2 f1 = __half22float2(o[qi][pi][1]);
        const float2 f2 = __half22float2(o[qi][pi][2]);
        const float2 f3 = __half22float2(o[qi][pi][3]);
        *(float4*)(dst + pi * 8) = make_float4(f0.x, f0.y, f1.x, f1.y);
        *(float4*)(dst + pi * 8 + 4) = make_float4(f2.x, f2.y, f3.x, f3.y);
      }
    }
  }
}

// ---------------- reduce: out_pre = bf16(p0 + p1) ----------------
__global__ __launch_bounds__(256) void reduce_k(const float* __restrict__ p,
                                                u16* __restrict__ out) {
  const size_t i = (size_t)blockIdx.x * 256 + threadIdx.x;   // granule of 8
  const float4 a0 = *(const float4*)(p + i * 8);
  const float4 a1 = *(const float4*)(p + i * 8 + 4);
  const float4 b0 = *(const float4*)(p + 2097152 + i * 8);
  const float4 b1 = *(const float4*)(p + 2097152 + i * 8 + 4);
  int4 pk;
  u16* pu = reinterpret_cast<u16*>(&pk);
  pu[0] = f2bf(a0.x + b0.x); pu[1] = f2bf(a0.y + b0.y);
  pu[2] = f2bf(a0.z + b0.z); pu[3] = f2bf(a0.w + b0.w);
  pu[4] = f2bf(a1.x + b1.x); pu[5] = f2bf(a1.y + b1.y);
  pu[6] = f2bf(a1.z + b1.z); pu[7] = f2bf(a1.w + b1.w);
  *(int4*)(out + i * 8) = pk;
}

// ---------------- host ----------------
extern "C" void kernel_launch(void* const* d_in, const int* in_sizes, int n_in,
                              void* d_out, int out_size, void* d_ws, size_t ws_size,
                              hipStream_t stream) {
  (void)in_sizes; (void)n_in; (void)out_size; (void)ws_size;
  char* wsp = (char*)d_ws;
  size_t off = 0;
  auto take = [&](size_t bytes) {
    void* p = (void*)(wsp + off);
    off += ((bytes + 255) & ~(size_t)255);
    return p;
  };

  static const int wR[10] = {128, 512, 512, 128, 512, 512, 128, 512, 512, 512};
  static const int wC[10] = {512, 512, 512, 512, 512, 512, 512, 512, 512, 128};
  static const int widx[10] = {3, 5, 7, 9, 11, 13, 15, 17, 19, 21};

  u16* WT[10];
  for (int i = 0; i < 10; ++i) WT[i] = (u16*)take((size_t)wR[i] * wC[i] * 2);
  u16* h1[3]; for (int i = 0; i < 3; ++i) h1[i] = (u16*)take((size_t)4096 * 512 * 2);
  u16* h2[3]; for (int i = 0; i < 3; ++i) h2[i] = (u16*)take((size_t)4096 * 512 * 2);
  float* partial = (float*)take((size_t)2 * 4096 * 512 * 4);

  TransArgs ta;
  for (int i = 0; i < 10; ++i) {
    ta.src[i] = (const float*)d_in[widx[i]];
    ta.dst[i] = WT[i];
    ta.R[i] = wR[i];
    ta.C[i] = wC[i];
  }
  hipLaunchKernelGGL(transpose_k, dim3(16, 16, 10), dim3(256), 0, stream, ta);

  // layer 1: [4096x128]@[128x512]+b, relu; A fp32  (z: 0=k/KEY, 1=q/QUERY, 2=v/VALUE)
  GemmArgs g1 = {};
  g1.A[0] = d_in[0]; g1.A[1] = d_in[2]; g1.A[2] = d_in[1];
  g1.WT[0] = WT[0]; g1.WT[1] = WT[3]; g1.WT[2] = WT[6];
  g1.bias[0] = (const float*)d_in[4]; g1.bias[1] = (const float*)d_in[10]; g1.bias[2] = (const float*)d_in[16];
  g1.C[0] = h1[0]; g1.C[1] = h1[1]; g1.C[2] = h1[2];
  hipLaunchKernelGGL(gemm_bias_act, dim3(8, 64, 3), dim3(256), 0, stream, g1, 4096, 512, 128, 1, 1, 0);

  // layer 2: [4096x512]@[512x512]+b, relu; A bf16, out bf16
  GemmArgs g2 = {};
  for (int i = 0; i < 3; ++i) { g2.A[i] = h1[i]; g2.C[i] = h2[i]; }
  g2.WT[0] = WT[1]; g2.WT[1] = WT[4]; g2.WT[2] = WT[7];
  g2.bias[0] = (const float*)d_in[6]; g2.bias[1] = (const float*)d_in[12]; g2.bias[2] = (const float*)d_in[18];
  hipLaunchKernelGGL(gemm_bias_act, dim3(8, 64, 3), dim3(256), 0, stream, g2, 4096, 512, 512, 1, 0, 0);

  // layer 3: [4096x512]@[512x512]+b, no act -> Km,Qm,Vm in h1[] as FP16
  GemmArgs g3 = {};
  for (int i = 0; i < 3; ++i) { g3.A[i] = h2[i]; g3.C[i] = h1[i]; }
  g3.WT[0] = WT[2]; g3.WT[1] = WT[5]; g3.WT[2] = WT[8];
  g3.bias[0] = (const float*)d_in[8]; g3.bias[1] = (const float*)d_in[14]; g3.bias[2] = (const float*)d_in[20];
  hipLaunchKernelGGL(gemm_bias_act, dim3(8, 64, 3), dim3(256), 0, stream, g3, 4096, 512, 512, 0, 0, 2);

  // fused attention (2-way key split) -> fp32 partials
  hipLaunchKernelGGL(attn_kernel, dim3(512), dim3(256), 0, stream, h1[0], h1[1], h1[2], partial);

  // reduce partials -> out_pre (bf16) in h2[0]
  hipLaunchKernelGGL(reduce_k, dim3(1024), dim3(256), 0, stream, partial, h2[0]);

  // final projection: [4096x512]@[512x128]+b -> d_out (fp32)
  GemmArgs g4 = {};
  g4.A[0] = h2[0]; g4.WT[0] = WT[9]; g4.bias[0] = (const float*)d_in[22]; g4.C[0] = d_out;
  hipLaunchKernelGGL(gemm_bias_act, dim3(2, 64, 1), dim3(256), 0, stream, g4, 4096, 128, 512, 0, 0, 1);
}

// Round 7
// 400.988 us; speedup vs baseline: 1.6430x; 1.2793x over previous
//
#include <hip/hip_runtime.h>
#include <hip/hip_bf16.h>
#include <hip/hip_fp16.h>

typedef unsigned short u16;
typedef __attribute__((ext_vector_type(8))) short short8;
typedef __attribute__((ext_vector_type(4))) float floatx4;

#define DEVI static __device__ __forceinline__

DEVI float bf2f(u16 b) { return __uint_as_float(((unsigned)b) << 16); }
DEVI u16 f2bf(float f) {
  __hip_bfloat16 h = __float2bfloat16(f);
  u16 u; __builtin_memcpy(&u, &h, 2); return u;
}
DEVI u16 f2h(float f) {
  __half h = __float2half(f);
  u16 u; __builtin_memcpy(&u, &h, 2); return u;
}

// DPP cross-lane add on float (VALU pipe)
template <int CTRL>
DEVI float dpp_add_f(float v) {
  int i; __builtin_memcpy(&i, &v, 4);
  int p = __builtin_amdgcn_update_dpp(0, i, CTRL, 0xF, 0xF, false);
  float pv; __builtin_memcpy(&pv, &p, 4);
  return v + pv;
}

// head-major permutation: feature f (= d*8+h) -> c' = h*64+d
DEVI int hperm(int f) { return ((f & 7) << 6) | (f >> 3); }

// ---------------- weight transpose + fp32->bf16: dst[C][R] = bf16(src[R][C]^T) ----------------
// z==9 (Wo): K-dim (rows of src) permuted head-major to match out_pre layout.
struct TransArgs {
  const float* src[10];
  u16* dst[10];
  int R[10];
  int C[10];
};

__global__ __launch_bounds__(256) void transpose_k(TransArgs t) {
  const int z = blockIdx.z;
  const float* __restrict__ src = t.src[z];
  u16* __restrict__ dst = t.dst[z];
  const int R = t.R[z], C = t.C[z];
  const int c0 = blockIdx.x * 32, r0 = blockIdx.y * 32;
  if (c0 >= C || r0 >= R) return;
  __shared__ float tile[32][33];
  const int tx = threadIdx.x & 31, ty = threadIdx.x >> 5;
  for (int i = ty; i < 32; i += 8)
    tile[i][tx] = src[(size_t)(r0 + i) * C + c0 + tx];
  __syncthreads();
  for (int i = ty; i < 32; i += 8) {
    const int f = r0 + tx;
    const int fi = (z == 9) ? hperm(f) : f;
    dst[(size_t)(c0 + i) * R + fi] = f2bf(tile[tx][i]);
  }
}

// ------------- GEMM: C[M][N] = act(A[M][K] @ W + bias), WT[N][K] bf16 given -------------
// c_mode: 0 = bf16 out, 1 = fp32 out, 2 = fp16 out.  out_perm: store col head-major.
struct GemmArgs {
  const void* A[3];      // fp32 if a_f32 else bf16
  const u16* WT[3];      // bf16
  const float* bias[3];  // fp32
  void* C[3];
};

__global__ __launch_bounds__(256) void gemm_bias_act(GemmArgs ga, int M, int N, int K,
                                                     int relu, int a_f32, int c_mode,
                                                     int out_perm) {
  const int z = blockIdx.z;
  const void* __restrict__ A = ga.A[z];
  const u16* __restrict__ WT = ga.WT[z];
  const float* __restrict__ bias = ga.bias[z];
  void* __restrict__ C = ga.C[z];

  __shared__ u16 As[64][72];
  __shared__ u16 Bs[64][72];

  const int tid = threadIdx.x;
  const int lane = tid & 63;
  const int wave = tid >> 6;
  const int wm = wave >> 1, wn = wave & 1;
  const int mb = blockIdx.y, nb = blockIdx.x;

  floatx4 acc0 = {0.f, 0.f, 0.f, 0.f}, acc1 = acc0, acc2 = acc0, acc3 = acc0;

  const int sr = tid >> 3;        // 0..31
  const int sc = (tid & 7) * 8;   // 0..56

  for (int k0 = 0; k0 < K; k0 += 64) {
    __syncthreads();
#pragma unroll
    for (int it = 0; it < 2; ++it) {
      const int rr = sr + it * 32;
      if (a_f32) {
        const float* Af = (const float*)A;
        const float4 f0 = *(const float4*)(Af + (size_t)(mb * 64 + rr) * K + k0 + sc);
        const float4 f1 = *(const float4*)(Af + (size_t)(mb * 64 + rr) * K + k0 + sc + 4);
        u16 tmp[8] = {f2bf(f0.x), f2bf(f0.y), f2bf(f0.z), f2bf(f0.w),
                      f2bf(f1.x), f2bf(f1.y), f2bf(f1.z), f2bf(f1.w)};
        int4 t; __builtin_memcpy(&t, tmp, 16);
        *(int4*)&As[rr][sc] = t;
      } else {
        const u16* Ab = (const u16*)A;
        *(int4*)&As[rr][sc] = *(const int4*)(Ab + (size_t)(mb * 64 + rr) * K + k0 + sc);
      }
      *(int4*)&Bs[rr][sc] = *(const int4*)(WT + (size_t)(nb * 64 + rr) * K + k0 + sc);
    }
    __syncthreads();
#pragma unroll
    for (int ks = 0; ks < 2; ++ks) {
      const int koff = ks * 32 + (lane >> 4) * 8;
      const int am = wm * 32 + (lane & 15);
      const int bn = wn * 32 + (lane & 15);
      short8 a0 = *(const short8*)&As[am][koff];
      short8 a1 = *(const short8*)&As[am + 16][koff];
      short8 b0 = *(const short8*)&Bs[bn][koff];
      short8 b1 = *(const short8*)&Bs[bn + 16][koff];
      acc0 = __builtin_amdgcn_mfma_f32_16x16x32_bf16(a0, b0, acc0, 0, 0, 0);
      acc1 = __builtin_amdgcn_mfma_f32_16x16x32_bf16(a0, b1, acc1, 0, 0, 0);
      acc2 = __builtin_amdgcn_mfma_f32_16x16x32_bf16(a1, b0, acc2, 0, 0, 0);
      acc3 = __builtin_amdgcn_mfma_f32_16x16x32_bf16(a1, b1, acc3, 0, 0, 0);
    }
  }

  const int colb = nb * 64 + wn * 32 + (lane & 15);
  const int rowb = mb * 64 + wm * 32 + (lane >> 4) * 4;
  const floatx4 accs[4] = {acc0, acc1, acc2, acc3};
#pragma unroll
  for (int mg = 0; mg < 2; ++mg) {
#pragma unroll
    for (int ng = 0; ng < 2; ++ng) {
      const int col = colb + ng * 16;
      const float bv = bias[col];
      const int colw = out_perm ? hperm(col) : col;
      const floatx4 v = accs[mg * 2 + ng];
#pragma unroll
      for (int r = 0; r < 4; ++r) {
        const int row = rowb + mg * 16 + r;
        float x = v[r] + bv;
        if (relu) x = fmaxf(x, 0.f);
        if (c_mode == 1)      ((float*)C)[(size_t)row * N + colw] = x;
        else if (c_mode == 2) ((u16*)C)[(size_t)row * N + colw] = f2h(x);
        else                  ((u16*)C)[(size_t)row * N + colw] = f2bf(x);
      }
    }
  }
}

// ---------------- fused attention v5 (head-major features) ----------------
// K,Q,V fp16 [b*1024][512], feature layout c' = h*64+d (head-major).
// Wave-autonomous: wid = blockIdx*4+wave -> (b, sp in 0..7, qt). 16 queries/wave.
// lane = (qg 0..3, h 0..7, half 0..1): queries {j0+qg+4*qi}, slice = 32 contiguous
// feats [h*64+half*32, +32) = 4 b128 granules (rotated by h for bank spread).
// d8 = intra-lane horizontal + one DPP(xor1) half-merge; softmax norm = 3-stage
// scalar-float DPP sum (masks 2,7,15 span the 8 heads); w is a scalar per (q,k).
// 2-key chunks staged to wave-private LDS (linear, conflict-free), reg prefetch.
// No barriers, no cross-wave reduce; o (fp16) written directly to partial[sp].
__global__ __launch_bounds__(256, 2) void attn_kernel(const u16* __restrict__ Km,
                                                      const u16* __restrict__ Qm,
                                                      const u16* __restrict__ Vm,
                                                      u16* __restrict__ partial) {
  __shared__ alignas(16) u16 lds[4 * 2048];   // per wave: K rows [0,1024), V rows [1024,2048) halfs

  const int tid = threadIdx.x;
  const int lane = tid & 63;
  const int wave = tid >> 6;
  const int wid = blockIdx.x * 4 + wave;      // 0..2047
  const int qt = wid & 63;
  const int sp = (wid >> 6) & 7;
  const int b = wid >> 9;
  const int j0 = qt * 16;

  const int qg = lane >> 4;
  const int h = (lane >> 1) & 7;
  const int half = lane & 1;

  // rotated granule indices of this lane's 32-feat slice (rotation spreads banks)
  int grans[4];
#pragma unroll
  for (int pi = 0; pi < 4; ++pi)
    grans[pi] = h * 8 + half * 4 + ((pi + h) & 3);

  // Q into registers: 4 queries x 4 granules (rotated order)
  int4 Qr[4][4];
#pragma unroll
  for (int qi = 0; qi < 4; ++qi) {
    const u16* qrow = Qm + (size_t)(b * 1024 + j0 + qg + qi * 4) * 512;
#pragma unroll
    for (int pi = 0; pi < 4; ++pi)
      Qr[qi][pi] = *(const int4*)(qrow + grans[pi] * 8);
  }

  __half2 o[4][4][4];   // [qi][pi][j]
#pragma unroll
  for (int qi = 0; qi < 4; ++qi)
#pragma unroll
    for (int pi = 0; pi < 4; ++pi)
#pragma unroll
      for (int j = 0; j < 4; ++j) o[qi][pi][j] = __float2half2_rn(0.f);

  u16* Kw = lds + wave * 2048;
  u16* Vw = Kw + 1024;
  const int keyBase = b * 1024 + sp * 128;

  int4 Kp[2], Vp[2];
#pragma unroll
  for (int r = 0; r < 2; ++r) {
    const size_t ga = (size_t)(keyBase + r) * 512 + lane * 8;
    Kp[r] = *(const int4*)(Km + ga);
    Vp[r] = *(const int4*)(Vm + ga);
  }

#pragma unroll 1
  for (int t = 0; t < 64; ++t) {
    // stage current 2-key chunk (linear: lane writes granule=lane; conflict-free)
#pragma unroll
    for (int r = 0; r < 2; ++r) {
      *(int4*)(Kw + r * 512 + lane * 8) = Kp[r];
      *(int4*)(Vw + r * 512 + lane * 8) = Vp[r];
    }
    // prefetch next chunk
    if (t < 63) {
#pragma unroll
      for (int r = 0; r < 2; ++r) {
        const size_t ga = (size_t)(keyBase + (t + 1) * 2 + r) * 512 + lane * 8;
        Kp[r] = *(const int4*)(Km + ga);
        Vp[r] = *(const int4*)(Vm + ga);
      }
    }

#pragma unroll
    for (int r = 0; r < 2; ++r) {
      const u16* krow = Kw + r * 512;
      // ---- cdist: packed fp16 L1 over the 32-feat slice, 4 queries
      __half2 acc[4][2];
#pragma unroll
      for (int qi = 0; qi < 4; ++qi) {
        acc[qi][0] = __float2half2_rn(0.f);
        acc[qi][1] = __float2half2_rn(0.f);
      }
#pragma unroll
      for (int pi = 0; pi < 4; ++pi) {
        const int4 kv = *(const int4*)(krow + grans[pi] * 8);
        const __half2* kh = reinterpret_cast<const __half2*>(&kv);
#pragma unroll
        for (int qi = 0; qi < 4; ++qi) {
          const __half2* qh = reinterpret_cast<const __half2*>(&Qr[qi][pi]);
          acc[qi][0] = __hadd2(acc[qi][0], __habs2(__hsub2(kh[0], qh[0])));
          acc[qi][1] = __hadd2(acc[qi][1], __habs2(__hsub2(kh[1], qh[1])));
          acc[qi][0] = __hadd2(acc[qi][0], __habs2(__hsub2(kh[2], qh[2])));
          acc[qi][1] = __hadd2(acc[qi][1], __habs2(__hsub2(kh[3], qh[3])));
        }
      }

      // ---- per-query: horizontal -> half-merge (xor1) -> softmax over heads
      __half2 wh[4];
#pragma unroll
      for (int qi = 0; qi < 4; ++qi) {
        const __half2 s2 = __hadd2(acc[qi][0], acc[qi][1]);
        float d8p = __half2float(__low2half(s2)) + __half2float(__high2half(s2));
        const float d8 = dpp_add_f<0xB1>(d8p);          // merge the two half-slices (lane^1)
        const float e = __expf(-0.5f * d8 * d8);        // p >= 0 -> e <= 1, no overflow
        float nrm = e;
        nrm = dpp_add_f<0x4E>(nrm);                     // lane^2
        nrm = dpp_add_f<0x141>(nrm);                    // row_half_mirror (lane^7)
        nrm = dpp_add_f<0x140>(nrm);                    // row_mirror (lane^15)
        const float w = e * __builtin_amdgcn_rcpf(nrm); // spans all 8 heads exactly once
        wh[qi] = __float2half2_rn(w);
      }

      // ---- PV: o += w * V over the slice
      const u16* vrow = Vw + r * 512;
#pragma unroll
      for (int pi = 0; pi < 4; ++pi) {
        const int4 vv = *(const int4*)(vrow + grans[pi] * 8);
        const __half2* vh = reinterpret_cast<const __half2*>(&vv);
#pragma unroll
        for (int qi = 0; qi < 4; ++qi) {
          o[qi][pi][0] = __hfma2(wh[qi], vh[0], o[qi][pi][0]);
          o[qi][pi][1] = __hfma2(wh[qi], vh[1], o[qi][pi][1]);
          o[qi][pi][2] = __hfma2(wh[qi], vh[2], o[qi][pi][2]);
          o[qi][pi][3] = __hfma2(wh[qi], vh[3], o[qi][pi][3]);
        }
      }
    }
  }

  // ---- store fp16 partial (head-major layout), unrotating granules
#pragma unroll
  for (int qi = 0; qi < 4; ++qi) {
    const int j = j0 + qg + qi * 4;
    u16* dst = partial + (size_t)sp * (4096 * 512) + (size_t)(b * 1024 + j) * 512;
#pragma unroll
    for (int pi = 0; pi < 4; ++pi) {
      int4 pk; __builtin_memcpy(&pk, &o[qi][pi][0], 16);
      *(int4*)(dst + grans[pi] * 8) = pk;
    }
  }
}

// ---------------- reduce: out_pre = bf16(sum of 8 fp16 partials) ----------------
__global__ __launch_bounds__(256) void reduce_k(const u16* __restrict__ p,
                                                u16* __restrict__ out) {
  const size_t i = ((size_t)blockIdx.x * 256 + threadIdx.x) * 8;   // granule of 8 halfs
  float s[8] = {0.f, 0.f, 0.f, 0.f, 0.f, 0.f, 0.f, 0.f};
#pragma unroll
  for (int sp = 0; sp < 8; ++sp) {
    const int4 t = *(const int4*)(p + (size_t)sp * (4096 * 512) + i);
    const __half* th = reinterpret_cast<const __half*>(&t);
#pragma unroll
    for (int j = 0; j < 8; ++j) s[j] += __half2float(th[j]);
  }
  int4 pk;
  u16* pu = reinterpret_cast<u16*>(&pk);
#pragma unroll
  for (int j = 0; j < 8; ++j) pu[j] = f2bf(s[j]);
  *(int4*)(out + i) = pk;
}

// ---------------- host ----------------
extern "C" void kernel_launch(void* const* d_in, const int* in_sizes, int n_in,
                              void* d_out, int out_size, void* d_ws, size_t ws_size,
                              hipStream_t stream) {
  (void)in_sizes; (void)n_in; (void)out_size; (void)ws_size;
  char* wsp = (char*)d_ws;
  size_t off = 0;
  auto take = [&](size_t bytes) {
    void* p = (void*)(wsp + off);
    off += ((bytes + 255) & ~(size_t)255);
    return p;
  };

  static const int wR[10] = {128, 512, 512, 128, 512, 512, 128, 512, 512, 512};
  static const int wC[10] = {512, 512, 512, 512, 512, 512, 512, 512, 512, 128};
  static const int widx[10] = {3, 5, 7, 9, 11, 13, 15, 17, 19, 21};

  u16* WT[10];
  for (int i = 0; i < 10; ++i) WT[i] = (u16*)take((size_t)wR[i] * wC[i] * 2);
  u16* h1[3]; for (int i = 0; i < 3; ++i) h1[i] = (u16*)take((size_t)4096 * 512 * 2);
  u16* h2[3]; for (int i = 0; i < 3; ++i) h2[i] = (u16*)take((size_t)4096 * 512 * 2);
  u16* partial = (u16*)take((size_t)8 * 4096 * 512 * 2);   // fp16, 8 key-splits

  TransArgs ta;
  for (int i = 0; i < 10; ++i) {
    ta.src[i] = (const float*)d_in[widx[i]];
    ta.dst[i] = WT[i];
    ta.R[i] = wR[i];
    ta.C[i] = wC[i];
  }
  hipLaunchKernelGGL(transpose_k, dim3(16, 16, 10), dim3(256), 0, stream, ta);

  // layer 1: [4096x128]@[128x512]+b, relu; A fp32  (z: 0=k/KEY, 1=q/QUERY, 2=v/VALUE)
  GemmArgs g1 = {};
  g1.A[0] = d_in[0]; g1.A[1] = d_in[2]; g1.A[2] = d_in[1];
  g1.WT[0] = WT[0]; g1.WT[1] = WT[3]; g1.WT[2] = WT[6];
  g1.bias[0] = (const float*)d_in[4]; g1.bias[1] = (const float*)d_in[10]; g1.bias[2] = (const float*)d_in[16];
  g1.C[0] = h1[0]; g1.C[1] = h1[1]; g1.C[2] = h1[2];
  hipLaunchKernelGGL(gemm_bias_act, dim3(8, 64, 3), dim3(256), 0, stream, g1, 4096, 512, 128, 1, 1, 0, 0);

  // layer 2: [4096x512]@[512x512]+b, relu; A bf16, out bf16
  GemmArgs g2 = {};
  for (int i = 0; i < 3; ++i) { g2.A[i] = h1[i]; g2.C[i] = h2[i]; }
  g2.WT[0] = WT[1]; g2.WT[1] = WT[4]; g2.WT[2] = WT[7];
  g2.bias[0] = (const float*)d_in[6]; g2.bias[1] = (const float*)d_in[12]; g2.bias[2] = (const float*)d_in[18];
  hipLaunchKernelGGL(gemm_bias_act, dim3(8, 64, 3), dim3(256), 0, stream, g2, 4096, 512, 512, 1, 0, 0, 0);

  // layer 3: -> Km,Qm,Vm fp16, HEAD-MAJOR feature layout
  GemmArgs g3 = {};
  for (int i = 0; i < 3; ++i) { g3.A[i] = h2[i]; g3.C[i] = h1[i]; }
  g3.WT[0] = WT[2]; g3.WT[1] = WT[5]; g3.WT[2] = WT[8];
  g3.bias[0] = (const float*)d_in[8]; g3.bias[1] = (const float*)d_in[14]; g3.bias[2] = (const float*)d_in[20];
  hipLaunchKernelGGL(gemm_bias_act, dim3(8, 64, 3), dim3(256), 0, stream, g3, 4096, 512, 512, 0, 0, 2, 1);

  // fused attention (8-way key split, wave-autonomous) -> fp16 partials
  hipLaunchKernelGGL(attn_kernel, dim3(512), dim3(256), 0, stream, h1[0], h1[1], h1[2], partial);

  // reduce partials -> out_pre (bf16, head-major) in h2[0]
  hipLaunchKernelGGL(reduce_k, dim3(1024), dim3(256), 0, stream, partial, h2[0]);

  // final projection: [4096x512]@[512x128]+b -> d_out (fp32); WT[9] K-dim permuted to match
  GemmArgs g4 = {};
  g4.A[0] = h2[0]; g4.WT[0] = WT[9]; g4.bias[0] = (const float*)d_in[22]; g4.C[0] = d_out;
  hipLaunchKernelGGL(gemm_bias_act, dim3(2, 64, 1), dim3(256), 0, stream, g4, 4096, 128, 512, 0, 0, 1, 0);
}